// Round 5
// baseline (493.896 us; speedup 1.0000x reference)
//
#include <hip/hip_runtime.h>
#include <stdint.h>

#define LOG2_HASHMAP_SIZE 19
#define HASHMAP_SIZE (1u << LOG2_HASHMAP_SIZE)
#define HASHMAP_MASK (HASHMAP_SIZE - 1u)
#define N_LEVELS 4
#define NBIN_1D 32
#define NBINS (NBIN_1D * NBIN_1D * NBIN_1D)   // 32768

__device__ __forceinline__ float2 level_embed_p(float px, float py, float pz,
                                                const float* __restrict__ tables,
                                                int li, float r)
{
    const uint32_t P1 = 11614769u;
    const uint32_t P2 = 2654435761u;

    const float sx = px * r, sy = py * r, sz = pz * r;
    const float bx = floorf(sx), by = floorf(sy), bz = floorf(sz);
    const float tx = sx - bx, ty = sy - by, tz = sz - bz;
    const float ux = 1.0f - tx, uy = 1.0f - ty, uz = 1.0f - tz;

    const uint32_t ix = (uint32_t)(int)bx;
    const uint32_t iy = (uint32_t)(int)by;
    const uint32_t iz = (uint32_t)(int)bz;

    const uint32_t hx0 = ix,      hx1 = ix + 1u;
    const uint32_t hy0 = iy * P1, hy1 = (iy + 1u) * P1;
    const uint32_t hz0 = iz * P2, hz1 = (iz + 1u) * P2;

    const float2* __restrict__ tab =
        (const float2*)(tables + (size_t)li * HASHMAP_SIZE * 2);

    float f0 = 0.0f, f1 = 0.0f;
    // corner c: x-offset = (c>>2)&1, y-offset = (c>>1)&1, z-offset = c&1
    #pragma unroll
    for (int c = 0; c < 8; ++c) {
        const uint32_t h = (((c & 4) ? hx1 : hx0)
                          ^ ((c & 2) ? hy1 : hy0)
                          ^ ((c & 1) ? hz1 : hz0)) & HASHMAP_MASK;
        const float2 e = tab[h];
        const float w = ((c & 4) ? tx : ux)
                      * ((c & 2) ? ty : uy)
                      * ((c & 1) ? tz : uz);
        f0 += w * e.x;
        f1 += w * e.y;
    }
    return make_float2(f0, f1);
}

__device__ __forceinline__ int bin_of(float px, float py, float pz)
{
    int bx = (int)(px * (float)NBIN_1D); bx = bx < 0 ? 0 : (bx > NBIN_1D - 1 ? NBIN_1D - 1 : bx);
    int by = (int)(py * (float)NBIN_1D); by = by < 0 ? 0 : (by > NBIN_1D - 1 ? NBIN_1D - 1 : by);
    int bz = (int)(pz * (float)NBIN_1D); bz = bz < 0 ? 0 : (bz > NBIN_1D - 1 ? NBIN_1D - 1 : bz);
    return (bx * NBIN_1D + by) * NBIN_1D + bz;
}

__global__ __launch_bounds__(256) void zero_hist_kernel(int* __restrict__ hist)
{
    const int i = blockIdx.x * blockDim.x + threadIdx.x;
    if (i < NBINS) hist[i] = 0;
}

__global__ __launch_bounds__(256) void hist_kernel(
    const float* __restrict__ x, int* __restrict__ hist, int n)
{
    const int i = blockIdx.x * blockDim.x + threadIdx.x;
    if (i >= n) return;
    const float px = x[3 * (size_t)i + 0];
    const float py = x[3 * (size_t)i + 1];
    const float pz = x[3 * (size_t)i + 2];
    atomicAdd(&hist[bin_of(px, py, pz)], 1);
}

// Exclusive prefix over 32768 bins; one workgroup of 1024 threads, 32 bins each.
__global__ __launch_bounds__(1024) void scan_kernel(
    const int* __restrict__ hist, int* __restrict__ cursor)
{
    __shared__ int partial[1024];
    const int t = threadIdx.x;
    const int base = t * 32;
    int local[32];
    int s = 0;
    #pragma unroll
    for (int j = 0; j < 32; ++j) { local[j] = s; s += hist[base + j]; }
    partial[t] = s;
    __syncthreads();
    for (int off = 1; off < 1024; off <<= 1) {
        int v = (t >= off) ? partial[t - off] : 0;
        __syncthreads();
        partial[t] += v;
        __syncthreads();
    }
    const int pre = (t == 0) ? 0 : partial[t - 1];
    #pragma unroll
    for (int j = 0; j < 32; ++j) cursor[base + j] = pre + local[j];
}

__global__ __launch_bounds__(256) void scatter_kernel(
    const float* __restrict__ x, int* __restrict__ cursor,
    float4* __restrict__ xs, int n)
{
    const int i = blockIdx.x * blockDim.x + threadIdx.x;
    if (i >= n) return;
    const float px = x[3 * (size_t)i + 0];
    const float py = x[3 * (size_t)i + 1];
    const float pz = x[3 * (size_t)i + 2];
    const int pos = atomicAdd(&cursor[bin_of(px, py, pz)], 1);
    float4 v;
    v.x = px; v.y = py; v.z = pz; v.w = __int_as_float(i);
    xs[pos] = v;
}

// Passes 0..2 over permuted points: dense float2 per-level results.
__global__ __launch_bounds__(256) void pass_ws_kernel(
    const float4* __restrict__ xs, const float* __restrict__ tables,
    float2* __restrict__ ws, int li, float r, int n)
{
    const int i = blockIdx.x * blockDim.x + threadIdx.x;
    if (i >= n) return;
    const float4 p = xs[i];
    ws[i] = level_embed_p(p.x, p.y, p.z, tables, li, r);
}

// Final: level 3 + combine, scatter-write to original point order.
__global__ __launch_bounds__(256) void final_kernel(
    const float4* __restrict__ xs, const float* __restrict__ tables,
    const float2* __restrict__ ws0, const float2* __restrict__ ws1,
    const float2* __restrict__ ws2, float* __restrict__ out, int n)
{
    const int i = blockIdx.x * blockDim.x + threadIdx.x;
    if (i >= n) return;
    const float4 p = xs[i];
    const int orig = __float_as_int(p.w);
    const float2 e3 = level_embed_p(p.x, p.y, p.z, tables, 3, 512.0f);
    const float2 e0 = ws0[i];
    const float2 e1 = ws1[i];
    const float2 e2 = ws2[i];
    float4* op = (float4*)(out + 8 * (size_t)orig);
    op[0] = make_float4(e0.x, e0.y, e1.x, e1.y);
    op[1] = make_float4(e2.x, e2.y, e3.x, e3.y);
}

// ---- fallback path (unsorted, round-2 structure) ----
__global__ __launch_bounds__(256) void pass_direct_kernel(
    const float* __restrict__ x, const float* __restrict__ tables,
    float* __restrict__ out, int li, float r, int n)
{
    const int i = blockIdx.x * blockDim.x + threadIdx.x;
    if (i >= n) return;
    const float px = x[3 * (size_t)i + 0];
    const float py = x[3 * (size_t)i + 1];
    const float pz = x[3 * (size_t)i + 2];
    const float2 e = level_embed_p(px, py, pz, tables, li, r);
    float2* op = (float2*)(out + 8 * (size_t)i + 2 * li);
    *op = e;
}

extern "C" void kernel_launch(void* const* d_in, const int* in_sizes, int n_in,
                              void* d_out, int out_size, void* d_ws, size_t ws_size,
                              hipStream_t stream) {
    const float* x = (const float*)d_in[0];        // [N, 3]
    const float* tables = (const float*)d_in[1];   // [4, 2^19, 2]
    float* out = (float*)d_out;                    // [N, 8]
    const int n = in_sizes[0] / 3;

    const float res[N_LEVELS] = {30.0f, 80.0f, 210.0f, 512.0f};
    const int block = 256;
    const int grid = (n + block - 1) / block;

    // ws layout: xs [n float4] | ws0,ws1,ws2 [n float2 each] | hist | cursor
    const size_t xs_bytes = (size_t)n * sizeof(float4);
    const size_t wsl_bytes = (size_t)n * sizeof(float2);
    const size_t ws_needed = xs_bytes + 3 * wsl_bytes + 2 * (size_t)NBINS * sizeof(int);

    if (ws_size >= ws_needed) {
        char* base = (char*)d_ws;
        float4* xs  = (float4*)base;
        float2* ws0 = (float2*)(base + xs_bytes);
        float2* ws1 = (float2*)(base + xs_bytes + wsl_bytes);
        float2* ws2 = (float2*)(base + xs_bytes + 2 * wsl_bytes);
        int* hist   = (int*)(base + xs_bytes + 3 * wsl_bytes);
        int* cursor = hist + NBINS;

        zero_hist_kernel<<<(NBINS + block - 1) / block, block, 0, stream>>>(hist);
        hist_kernel<<<grid, block, 0, stream>>>(x, hist, n);
        scan_kernel<<<1, 1024, 0, stream>>>(hist, cursor);
        scatter_kernel<<<grid, block, 0, stream>>>(x, cursor, xs, n);

        for (int li = 0; li < 3; ++li) {
            float2* wsl = (li == 0) ? ws0 : (li == 1) ? ws1 : ws2;
            pass_ws_kernel<<<grid, block, 0, stream>>>(xs, tables, wsl, li, res[li], n);
        }
        final_kernel<<<grid, block, 0, stream>>>(xs, tables, ws0, ws1, ws2, out, n);
    } else {
        for (int li = 0; li < N_LEVELS; ++li) {
            pass_direct_kernel<<<grid, block, 0, stream>>>(x, tables, out, li, res[li], n);
        }
    }
}

// Round 6
// 282.460 us; speedup vs baseline: 1.7485x; 1.7485x over previous
//
#include <hip/hip_runtime.h>
#include <stdint.h>

#define LOG2_HASHMAP_SIZE 19
#define HASHMAP_SIZE (1u << LOG2_HASHMAP_SIZE)
#define HASHMAP_MASK (HASHMAP_SIZE - 1u)
#define N_LEVELS 4

// Per level: h = ix ^ iy*P1 ^ iz*P2 (masked). XOR-linear in ix, so for even ix
// the x-corner pair {ix, ix+1} lands in the aligned table pair {h&~1, h|1} ->
// one float4 load returns both corners' float2 embeddings.
__device__ __forceinline__ float2 level_embed_p(float px, float py, float pz,
                                                const float* __restrict__ tables,
                                                int li, float r)
{
    const uint32_t P1 = 11614769u;
    const uint32_t P2 = 2654435761u;

    const float sx = px * r, sy = py * r, sz = pz * r;
    const float bx = floorf(sx), by = floorf(sy), bz = floorf(sz);
    const float tx = sx - bx, ty = sy - by, tz = sz - bz;
    const float ux = 1.0f - tx, uy = 1.0f - ty, uz = 1.0f - tz;

    const uint32_t ix = (uint32_t)(int)bx;
    const uint32_t iy = (uint32_t)(int)by;
    const uint32_t iz = (uint32_t)(int)bz;

    const uint32_t hy0 = iy * P1, hy1 = (iy + 1u) * P1;
    const uint32_t hz0 = iz * P2, hz1 = (iz + 1u) * P2;

    // 4 (y,z) corner combos: yz-hash part and yz-weight
    uint32_t S[4];
    float W[4];
    S[0] = hy0 ^ hz0;  W[0] = uy * uz;
    S[1] = hy0 ^ hz1;  W[1] = uy * tz;
    S[2] = hy1 ^ hz0;  W[2] = ty * uz;
    S[3] = hy1 ^ hz1;  W[3] = ty * tz;

    const float* tab = tables + (size_t)li * HASHMAP_SIZE * 2;
    const float2* __restrict__ tab2 = (const float2*)tab;
    const float4* __restrict__ tab4 = (const float4*)tab;

    float f0 = 0.0f, f1 = 0.0f;

    if ((ix & 1u) == 0u) {
        // even ix: one aligned float4 per (y,z) combo covers both x-corners
        #pragma unroll
        for (int c = 0; c < 4; ++c) {
            const uint32_t h0 = (ix ^ S[c]) & HASHMAP_MASK;   // x-corner 0
            const float4 v = tab4[h0 >> 1];                   // entries {h0&~1, h0|1}
            // if h0 even: x0 = v.xy, x1(h0^1=h0+1) = v.zw ; if h0 odd: swapped
            const bool hi = (h0 & 1u);
            const float e0x = hi ? v.z : v.x;
            const float e0y = hi ? v.w : v.y;
            const float e1x = hi ? v.x : v.z;
            const float e1y = hi ? v.y : v.w;
            f0 += W[c] * (ux * e0x + tx * e1x);
            f1 += W[c] * (ux * e0y + tx * e1y);
        }
    } else {
        // odd ix: {ix, ix+1} straddles aligned pairs; two float2 gathers
        #pragma unroll
        for (int c = 0; c < 4; ++c) {
            const uint32_t h0 = (ix ^ S[c]) & HASHMAP_MASK;
            const uint32_t h1 = ((ix + 1u) ^ S[c]) & HASHMAP_MASK;
            const float2 e0 = tab2[h0];
            const float2 e1 = tab2[h1];
            f0 += W[c] * (ux * e0.x + tx * e1.x);
            f1 += W[c] * (ux * e0.y + tx * e1.y);
        }
    }
    return make_float2(f0, f1);
}

// Passes 0..2: write dense per-level float2 results into workspace.
__global__ __launch_bounds__(256) void pass_ws_kernel(
    const float* __restrict__ x, const float* __restrict__ tables,
    float2* __restrict__ ws, int li, float r, int n)
{
    const int i = blockIdx.x * blockDim.x + threadIdx.x;
    if (i >= n) return;
    const float px = x[3 * (size_t)i + 0];
    const float py = x[3 * (size_t)i + 1];
    const float pz = x[3 * (size_t)i + 2];
    ws[i] = level_embed_p(px, py, pz, tables, li, r);
}

// Final pass: compute level 3, read ws levels 0..2, write [N,8] out.
__global__ __launch_bounds__(256) void final_kernel(
    const float* __restrict__ x, const float* __restrict__ tables,
    const float2* __restrict__ ws0, const float2* __restrict__ ws1,
    const float2* __restrict__ ws2, float* __restrict__ out, int n)
{
    const int i = blockIdx.x * blockDim.x + threadIdx.x;
    if (i >= n) return;
    const float px = x[3 * (size_t)i + 0];
    const float py = x[3 * (size_t)i + 1];
    const float pz = x[3 * (size_t)i + 2];
    const float2 e3 = level_embed_p(px, py, pz, tables, 3, 512.0f);
    const float2 e0 = ws0[i];
    const float2 e1 = ws1[i];
    const float2 e2 = ws2[i];
    float4* op = (float4*)(out + 8 * (size_t)i);
    op[0] = make_float4(e0.x, e0.y, e1.x, e1.y);
    op[1] = make_float4(e2.x, e2.y, e3.x, e3.y);
}

// Fallback (ws too small): per-level pass writing strided into out directly.
__global__ __launch_bounds__(256) void pass_direct_kernel(
    const float* __restrict__ x, const float* __restrict__ tables,
    float* __restrict__ out, int li, float r, int n)
{
    const int i = blockIdx.x * blockDim.x + threadIdx.x;
    if (i >= n) return;
    const float px = x[3 * (size_t)i + 0];
    const float py = x[3 * (size_t)i + 1];
    const float pz = x[3 * (size_t)i + 2];
    const float2 e = level_embed_p(px, py, pz, tables, li, r);
    float2* op = (float2*)(out + 8 * (size_t)i + 2 * li);
    *op = e;
}

extern "C" void kernel_launch(void* const* d_in, const int* in_sizes, int n_in,
                              void* d_out, int out_size, void* d_ws, size_t ws_size,
                              hipStream_t stream) {
    const float* x = (const float*)d_in[0];        // [N, 3]
    const float* tables = (const float*)d_in[1];   // [4, 2^19, 2]
    float* out = (float*)d_out;                    // [N, 8]
    const int n = in_sizes[0] / 3;

    const float res[N_LEVELS] = {30.0f, 80.0f, 210.0f, 512.0f};
    const int block = 256;
    const int grid = (n + block - 1) / block;

    const size_t ws_needed = 3 * (size_t)n * sizeof(float2);
    if (ws_size >= ws_needed) {
        float2* ws = (float2*)d_ws;
        for (int li = 0; li < 3; ++li) {
            pass_ws_kernel<<<grid, block, 0, stream>>>(
                x, tables, ws + (size_t)li * n, li, res[li], n);
        }
        final_kernel<<<grid, block, 0, stream>>>(
            x, tables, ws, ws + (size_t)n, ws + 2 * (size_t)n, out, n);
    } else {
        for (int li = 0; li < N_LEVELS; ++li) {
            pass_direct_kernel<<<grid, block, 0, stream>>>(
                x, tables, out, li, res[li], n);
        }
    }
}